// Round 5
// baseline (213.773 us; speedup 1.0000x reference)
//
#include <hip/hip_runtime.h>

// entmax-1.5 n-section loss. Monolithic 512-thread block per row.
//
// X:(n=4096, c=32000) fp32, rows ~ N(0,1). Xs = X/2; tau in [mx-1, mx]
// (Xs units) via 9 iters of 4-section search on f(tau)=sum relu(Xs-tau)^2-1.
// Only elements with raw x > rowmax - 2 ever contribute (tau >= mx-1).
//
// vs round 4 (162.5 us): 512-thr blocks -> 4 resident blocks/CU (was 2 of
// 1024 thr), so per-row serial tails hide 4-way under neighbors' streams;
// stream is software-pipelined (double-buffered 4xfloat4 batches, next batch
// in flight during ballot-compaction of current); search is block-parallel
// (all 8 waves, double-buffered LDS partials, 1 barrier/iter) so the block
// retires quickly and frees its CU slot.

#define NITER 9
#define NTHR  512
#define NWAVE 8
#define TGRAW 1.5f      // fixed raw-x prefilter (N(0,1) rows)
#define CAPW  512       // per-wave superset cap (mean 267, sd 16 -> 15 sigma)
#define EXCAP 3072      // exact candidate cap (worst accepted case ~2200)

__device__ __forceinline__ float wave_max_f(float m) {
    #pragma unroll
    for (int off = 32; off > 0; off >>= 1) m = fmaxf(m, __shfl_xor(m, off));
    return m;
}
__device__ __forceinline__ float wave_sum_f(float s) {
    #pragma unroll
    for (int off = 32; off > 0; off >>= 1) s += __shfl_xor(s, off);
    return s;
}

__global__ __launch_bounds__(NTHR, 8)
void entmax_loss_kernel(const float* __restrict__ X,
                        const int* __restrict__ target,
                        float* __restrict__ row_loss, int c) {
    const int r    = blockIdx.x;
    const int tid  = threadIdx.x;
    const int w    = tid >> 6;
    const int lane = tid & 63;
    const float* __restrict__ Xr = X + (size_t)r * (size_t)c;

    __shared__ float seg[NWAVE][CAPW];
    __shared__ int   segcnt[NWAVE];
    __shared__ float s_red[NWAVE];
    __shared__ int   s_excnt[NWAVE];
    __shared__ float ex[EXCAP];
    __shared__ float s_part[2][3][NWAVE];
    __shared__ float s_fin[3][NWAVE];
    __shared__ int   s_flag;
    __shared__ float s_xtg;

    if (tid == 0) { s_flag = 0; s_xtg = Xr[target[r]]; }

    // ---- phase 1: pipelined stream + wave max + superset ballot-gather ----
    const int c4 = c >> 2;                  // launcher: c%4==0, c<=32768
    const unsigned long long lt = (1ull << lane) - 1ull;
    float* __restrict__ segw = seg[w];
    float m = -3e38f;
    int   cnt = 0;

    float4 cur[4], nxt[4];
    #pragma unroll
    for (int k = 0; k < 4; ++k) {
        const int i4 = tid + k * NTHR;
        if (i4 < c4) cur[k] = ((const float4*)Xr)[i4];
        else { cur[k].x = cur[k].y = cur[k].z = cur[k].w = -3e38f; }
    }
    #pragma unroll
    for (int b = 0; b < 4; ++b) {
        if (b < 3) {                        // issue next batch before processing
            #pragma unroll
            for (int k = 0; k < 4; ++k) {
                const int i4 = tid + ((b + 1) * 4 + k) * NTHR;
                if (i4 < c4) nxt[k] = ((const float4*)Xr)[i4];
                else { nxt[k].x = nxt[k].y = nxt[k].z = nxt[k].w = -3e38f; }
            }
        }
        #pragma unroll
        for (int k = 0; k < 4; ++k) {
            const float e[4] = {cur[k].x, cur[k].y, cur[k].z, cur[k].w};
            m = fmaxf(m, fmaxf(fmaxf(e[0], e[1]), fmaxf(e[2], e[3])));
            #pragma unroll
            for (int j = 0; j < 4; ++j) {
                const bool p = e[j] > TGRAW;
                const unsigned long long bl = __ballot(p);
                const int pos = cnt + (int)__popcll(bl & lt);
                if (p && pos < CAPW) segw[pos] = e[j];
                cnt += (int)__popcll(bl);
            }
        }
        if (b < 3) {
            #pragma unroll
            for (int k = 0; k < 4; ++k) cur[k] = nxt[k];
        }
    }
    m = wave_max_f(m);
    if (lane == 0) {
        s_red[w] = m;
        segcnt[w] = cnt;
        if (cnt > CAPW) s_flag = 1;         // benign race: all writers store 1
    }
    __syncthreads();

    float rm = s_red[0];
    #pragma unroll
    for (int i = 1; i < NWAVE; ++i) rm = fmaxf(rm, s_red[i]);
    const bool fb = (s_flag != 0) || (rm < TGRAW + 2.0f);

    if (!fb) {
        // ---- phase 2a: count exact keepers (x > rm-2) per wave segment ----
        const float thr = rm - 2.0f;
        const int sc = segcnt[w];
        int ec = 0;
        for (int i0 = 0; i0 < sc; i0 += 64) {
            const int i = i0 + lane;
            const bool p = (i < sc) && (segw[i] > thr);
            ec += (int)__popcll(__ballot(p));
        }
        if (lane == 0) s_excnt[w] = ec;
        __syncthreads();

        int off = 0, total = 0;
        #pragma unroll
        for (int u = 0; u < NWAVE; ++u) {
            const int e = s_excnt[u];
            if (u < w) off += e;
            total += e;
        }
        if (total <= EXCAP) {               // uniform branch
            // ---- phase 2b: compact exact set (store Xs = x/2) ----
            int pos = off;
            for (int i0 = 0; i0 < sc; i0 += 64) {
                const int i = i0 + lane;
                const bool p = (i < sc) && (segw[i] > thr);
                const unsigned long long bl = __ballot(p);
                if (p) ex[pos + (int)__popcll(bl & lt)] = 0.5f * segw[i];
                pos += (int)__popcll(bl);
            }
            __syncthreads();
            // ---- phase 2c: block-parallel search, 1 barrier/iter ----
            float lo = 0.5f * rm - 1.0f, hi = 0.5f * rm;
            for (int it = 0; it < NITER; ++it) {
                const float w4 = (hi - lo) * 0.25f;
                const float t1 = lo + w4, t2 = lo + 2.f * w4, t3 = lo + 3.f * w4;
                float f1 = 0.f, f2 = 0.f, f3 = 0.f;
                for (int i = tid; i < total; i += NTHR) {
                    const float x = ex[i];
                    float d;
                    d = fmaxf(x - t1, 0.f); f1 = fmaf(d, d, f1);
                    d = fmaxf(x - t2, 0.f); f2 = fmaf(d, d, f2);
                    d = fmaxf(x - t3, 0.f); f3 = fmaf(d, d, f3);
                }
                f1 = wave_sum_f(f1); f2 = wave_sum_f(f2); f3 = wave_sum_f(f3);
                const int pb = it & 1;
                if (lane == 0) {
                    s_part[pb][0][w] = f1; s_part[pb][1][w] = f2; s_part[pb][2][w] = f3;
                }
                __syncthreads();
                float a = 0.f, bb = 0.f, g = 0.f;
                #pragma unroll
                for (int u = 0; u < NWAVE; ++u) {
                    a += s_part[pb][0][u]; bb += s_part[pb][1][u]; g += s_part[pb][2][u];
                }
                const int cc = (a >= 1.f) + (bb >= 1.f) + (g >= 1.f);
                lo += w4 * (float)cc;
                hi = lo + w4;
            }
            const float tau = 0.5f * (lo + hi);
            float S1 = 0.f, SX = 0.f, S3 = 0.f;
            for (int i = tid; i < total; i += NTHR) {
                const float x = ex[i];
                const float d = fmaxf(x - tau, 0.f), q = d * d;
                S1 += q; SX = fmaf(q, x, SX); S3 = fmaf(q, d, S3);
            }
            S1 = wave_sum_f(S1); SX = wave_sum_f(SX); S3 = wave_sum_f(S3);
            if (lane == 0) { s_fin[0][w] = S1; s_fin[1][w] = SX; s_fin[2][w] = S3; }
            __syncthreads();
            if (tid == 0) {
                float a = 0.f, bb = 0.f, g = 0.f;
                #pragma unroll
                for (int u = 0; u < NWAVE; ++u) {
                    a += s_fin[0][u]; bb += s_fin[1][u]; g += s_fin[2][u];
                }
                const float omega = (1.f - g / (a * sqrtf(a))) * (4.f / 3.f);
                row_loss[r] = omega + 2.f * bb / a - s_xtg;
            }
            return;
        }
        // total > EXCAP (uniform): fall through to full-rescan fallback
    }

    // ---- fallback: full multi-wave re-scan from global (rare) ----
    {
        float lo = 0.5f * rm - 1.0f, hi = 0.5f * rm;    // rm exact even here
        for (int it = 0; it < NITER; ++it) {
            const float w4 = (hi - lo) * 0.25f;
            const float t1 = lo + w4, t2 = lo + 2.f * w4, t3 = lo + 3.f * w4;
            float f1 = 0.f, f2 = 0.f, f3 = 0.f;
            for (int i = tid; i < c; i += NTHR) {
                const float x = 0.5f * Xr[i];
                float d;
                d = fmaxf(x - t1, 0.f); f1 = fmaf(d, d, f1);
                d = fmaxf(x - t2, 0.f); f2 = fmaf(d, d, f2);
                d = fmaxf(x - t3, 0.f); f3 = fmaf(d, d, f3);
            }
            f1 = wave_sum_f(f1); f2 = wave_sum_f(f2); f3 = wave_sum_f(f3);
            __syncthreads();
            if (lane == 0) { s_fin[0][w] = f1; s_fin[1][w] = f2; s_fin[2][w] = f3; }
            __syncthreads();
            float a = 0.f, bb = 0.f, g = 0.f;
            #pragma unroll
            for (int u = 0; u < NWAVE; ++u) {
                a += s_fin[0][u]; bb += s_fin[1][u]; g += s_fin[2][u];
            }
            const int cc = (a >= 1.f) + (bb >= 1.f) + (g >= 1.f);
            lo += w4 * (float)cc;
            hi = lo + w4;
        }
        const float tau = 0.5f * (lo + hi);
        float S1 = 0.f, SX = 0.f, S3 = 0.f;
        for (int i = tid; i < c; i += NTHR) {
            const float x = 0.5f * Xr[i];
            const float d = fmaxf(x - tau, 0.f), q = d * d;
            S1 += q; SX = fmaf(q, x, SX); S3 = fmaf(q, d, S3);
        }
        S1 = wave_sum_f(S1); SX = wave_sum_f(SX); S3 = wave_sum_f(S3);
        __syncthreads();
        if (lane == 0) { s_fin[0][w] = S1; s_fin[1][w] = SX; s_fin[2][w] = S3; }
        __syncthreads();
        if (tid == 0) {
            float a = 0.f, bb = 0.f, g = 0.f;
            #pragma unroll
            for (int u = 0; u < NWAVE; ++u) {
                a += s_fin[0][u]; bb += s_fin[1][u]; g += s_fin[2][u];
            }
            const float omega = (1.f - g / (a * sqrtf(a))) * (4.f / 3.f);
            row_loss[r] = omega + 2.f * bb / a - s_xtg;
        }
    }
}

// ---------------------------------------------------------------------------
// general fallback kernel (c%4!=0 or c>32768): wave-per-row full scan
// ---------------------------------------------------------------------------
__global__ __launch_bounds__(256, 4)
void fallback_kernel(const float* __restrict__ X, const int* __restrict__ target,
                     float* __restrict__ row_loss, int n, int c) {
    const int wv   = threadIdx.x >> 6;
    const int lane = threadIdx.x & 63;
    const int r = blockIdx.x * 4 + wv;
    if (r >= n) return;
    const float* __restrict__ Xr = X + (size_t)r * (size_t)c;
    float m = -3e38f;
    for (int i = lane; i < c; i += 64) m = fmaxf(m, Xr[i]);
    m = wave_max_f(m);
    float lo = 0.5f * m - 1.0f, hi = 0.5f * m;
    for (int it = 0; it < NITER; ++it) {
        const float w4 = (hi - lo) * 0.25f;
        const float t1 = lo + w4, t2 = lo + 2.f * w4, t3 = lo + 3.f * w4;
        float f1 = 0.f, f2 = 0.f, f3 = 0.f;
        for (int i = lane; i < c; i += 64) {
            const float x = 0.5f * Xr[i];
            float d;
            d = fmaxf(x - t1, 0.f); f1 = fmaf(d, d, f1);
            d = fmaxf(x - t2, 0.f); f2 = fmaf(d, d, f2);
            d = fmaxf(x - t3, 0.f); f3 = fmaf(d, d, f3);
        }
        f1 = wave_sum_f(f1); f2 = wave_sum_f(f2); f3 = wave_sum_f(f3);
        const int cc = (f1 >= 1.f) + (f2 >= 1.f) + (f3 >= 1.f);
        lo += w4 * (float)cc;
        hi = lo + w4;
    }
    const float tau = 0.5f * (lo + hi);
    float S1 = 0.f, SX = 0.f, S3 = 0.f;
    for (int i = lane; i < c; i += 64) {
        const float x = 0.5f * Xr[i];
        const float d = fmaxf(x - tau, 0.f), q = d * d;
        S1 += q; SX = fmaf(q, x, SX); S3 = fmaf(q, d, S3);
    }
    S1 = wave_sum_f(S1); SX = wave_sum_f(SX); S3 = wave_sum_f(S3);
    if (lane == 0) {
        const float omega = (1.f - S3 / (S1 * sqrtf(S1))) * (4.f / 3.f);
        row_loss[r] = omega + 2.f * SX / S1 - Xr[target[r]];
    }
}

// ---------------------------------------------------------------------------
__global__ __launch_bounds__(1024)
void reduce_mean_kernel(const float* __restrict__ vv, float* __restrict__ out, int n) {
    __shared__ float s_red[16];
    float s = 0.f;
    for (int i = threadIdx.x; i < n; i += 1024) s += vv[i];
    s = wave_sum_f(s);
    const int wv = threadIdx.x >> 6;
    const int lane = threadIdx.x & 63;
    if (lane == 0) s_red[wv] = s;
    __syncthreads();
    if (threadIdx.x == 0) {
        float t = 0.f;
        for (int i = 0; i < 16; ++i) t += s_red[i];
        out[0] = t / (float)n;
    }
}

extern "C" void kernel_launch(void* const* d_in, const int* in_sizes, int n_in,
                              void* d_out, int out_size, void* d_ws, size_t ws_size,
                              hipStream_t stream) {
    (void)n_in; (void)out_size;
    const float* X      = (const float*)d_in[0];
    const int*   target = (const int*)d_in[1];
    float*       out    = (float*)d_out;
    float*       row_loss = (float*)d_ws;

    const int n = in_sizes[1];
    const int c = in_sizes[0] / n;

    const bool fast = ((c & 3) == 0) && (c <= 32768) &&
                      (ws_size >= (size_t)n * sizeof(float));
    if (fast) {
        entmax_loss_kernel<<<n, NTHR, 0, stream>>>(X, target, row_loss, c);
    } else {
        fallback_kernel<<<(n + 3) / 4, 256, 0, stream>>>(X, target, row_loss, n, c);
    }
    reduce_mean_kernel<<<1, 1024, 0, stream>>>(row_loss, out, n);
}